// Round 7
// baseline (351.081 us; speedup 1.0000x reference)
//
#include <hip/hip_runtime.h>
#include <cstdint>
#include <cstddef>

#define B_ 32
#define N_ 512
#define H_ 256
#define S_ 3
#define BN_ (B_*N_)            // 16384
#define HH_ (H_*H_)            // 65536
#define BIGF 3.4028234e+38f
#define EPSF 1e-5f
#define SF_ ((long)N_ * H_)    // 131072
#define SVT_ ((long)H_ * N_)   // 131072

typedef __bf16 bf16x8 __attribute__((ext_vector_type(8)));
typedef float  f32x4  __attribute__((ext_vector_type(4)));

typedef const void __attribute__((address_space(1)))* gas_t;
typedef void __attribute__((address_space(3)))* las_t;

// async global->LDS, 16B per lane. LDS dest must be wave-uniform base + lane*16.
__device__ __forceinline__ void async16(const unsigned short* g, unsigned short* l) {
  __builtin_amdgcn_global_load_lds((gas_t)g, (las_t)l, 16, 0, 0);
}

// counted vmcnt wait + raw barrier pair (used in gemm_body only)
#define VMW(n) asm volatile("s_waitcnt vmcnt(" #n ")" ::: "memory")
#define SB()   __builtin_amdgcn_s_barrier()
#define SC0()  __builtin_amdgcn_sched_barrier(0)

__device__ __forceinline__ unsigned short f2bf(float f) {
  __bf16 h = (__bf16)f;
  unsigned short s;
  __builtin_memcpy(&s, &h, 2);
  return s;
}
__device__ __forceinline__ float bf2f(unsigned short u) {
  unsigned int v = ((unsigned int)u) << 16;
  float f;
  __builtin_memcpy(&f, &v, 4);
  return f;
}

// XOR-swizzle for 32-short (64B) LDS rows, 4 chunks of 8 shorts.
#define KC_STAGE(lane) ((((lane) & 3) ^ (((lane) >> 3) & 3)) * 8)
#define KC_READ(quad, l15) ((((quad) ^ (((l15) >> 1) & 3))) * 8)

// ------------- all 5 weight tensors -> bf16 in one dispatch -------------
__global__ __launch_bounds__(256) void cvt_all_k(
    const float* __restrict__ WQ, const float* __restrict__ WK,
    const float* __restrict__ WV, const float* __restrict__ W1,
    const float* __restrict__ W2,
    unsigned short* __restrict__ wqk, unsigned short* __restrict__ wv,
    unsigned short* __restrict__ w1, unsigned short* __restrict__ w2) {
  const int per = S_ * HH_ / 4;
  int gi = blockIdx.x * 256 + threadIdx.x;
  int which = gi / per;
  int e4 = gi - which * per;
  float4 v;
  if      (which == 0) v = ((const float4*)WQ)[e4];
  else if (which == 1) v = ((const float4*)WK)[e4];
  else if (which == 2) v = ((const float4*)WV)[e4];
  else if (which == 3) v = ((const float4*)W1)[e4];
  else                 v = ((const float4*)W2)[e4];
  ushort4 o;
  o.x = f2bf(v.x); o.y = f2bf(v.y); o.z = f2bf(v.z); o.w = f2bf(v.w);
  int e = e4 * 4;
  if (which <= 1) {
    int L = e / HH_, off = e - L * HH_;
    *(ushort4*)&wqk[(size_t)L * 2 * HH_ + (which == 1 ? HH_ : 0) + off] = o;
  } else if (which == 2) ((ushort4*)wv)[e4] = o;
  else if   (which == 3) ((ushort4*)w1)[e4] = o;
  else                   ((ushort4*)w2)[e4] = o;
}

// ------------- f_bf = bf16(x * mask_row) -------------
__global__ __launch_bounds__(256) void mask_mul_k(
    const float* __restrict__ x, const float* __restrict__ masks,
    unsigned short* __restrict__ fb) {
  int i = blockIdx.x * 256 + threadIdx.x;
  int row = i >> 6;
  float m = masks[row];
  float4 v = ((const float4*)x)[i];
  ushort4 o;
  o.x = f2bf(v.x * m); o.y = f2bf(v.y * m); o.z = f2bf(v.z * m); o.w = f2bf(v.w * m);
  ((ushort4*)fb)[i] = o;
}

// ================= MFMA GEMM body (128x128, BK=32, dbuf, counted vmcnt, 2-barrier) =================
// C = A(bf16,[m][k],lda) @ B(bf16,[n][k],ldb)^T   (bf16 out)
__device__ __forceinline__ void gemm_body(
    const unsigned short* __restrict__ A, const unsigned short* __restrict__ Bm,
    unsigned short* __restrict__ Cb,
    int K, int Nn, int lda, int ldb, long sA, long sB, long sC,
    int b, int m0, int n0, int t,
    unsigned short (&As)[2][128 * 32], unsigned short (&Bs)[2][128 * 32]) {
  const int wave = t >> 6, lane = t & 63;
  const int wm = wave >> 1, wn = wave & 1;
  const int quad = lane >> 4, l15 = lane & 15;
  const int srow = lane >> 2;
  const int kc = KC_STAGE(lane);
  const int pos8 = (lane & 3) * 8;

  const unsigned short* pa0 = A + (size_t)b * sA + (size_t)(m0 + wave * 32 + srow) * lda + kc;
  const unsigned short* pa1 = pa0 + 16 * (size_t)lda;
  const unsigned short* pb0 = Bm + (size_t)b * sB + (size_t)(n0 + wave * 32 + srow) * ldb + kc;
  const unsigned short* pb1 = pb0 + 16 * (size_t)ldb;
  const int lo = (wave * 32 + srow) * 32 + pos8;

  f32x4 acc[4][4];
#pragma unroll
  for (int i = 0; i < 4; ++i)
#pragma unroll
    for (int j = 0; j < 4; ++j) acc[i][j] = (f32x4){0.f, 0.f, 0.f, 0.f};

  const int soff = KC_READ(quad, l15);
  const int NT = K >> 5;
  // prologue: issue tile 0 (no drain)
  async16(pa0, &As[0][lo]); async16(pa1, &As[0][lo + 16 * 32]);
  async16(pb0, &Bs[0][lo]); async16(pb1, &Bs[0][lo + 16 * 32]);
  int cur = 0;
  for (int tt = 0; tt < NT; ++tt) {
    if (tt + 1 < NT) {
      const int kn = (tt + 1) << 5;
      async16(pa0 + kn, &As[cur ^ 1][lo]); async16(pa1 + kn, &As[cur ^ 1][lo + 16 * 32]);
      async16(pb0 + kn, &Bs[cur ^ 1][lo]); async16(pb1 + kn, &Bs[cur ^ 1][lo + 16 * 32]);
      VMW(4);                       // tile tt landed; tile tt+1 stays in flight
    } else VMW(0);
    SB(); SC0();                    // data-ready barrier
    bf16x8 af[4], bfr[4];
#pragma unroll
    for (int i = 0; i < 4; ++i)
      af[i] = *(const bf16x8*)&As[cur][(wm * 64 + i * 16 + l15) * 32 + soff];
#pragma unroll
    for (int j = 0; j < 4; ++j)
      bfr[j] = *(const bf16x8*)&Bs[cur][(wn * 64 + j * 16 + l15) * 32 + soff];
#pragma unroll
    for (int i = 0; i < 4; ++i)
#pragma unroll
      for (int j = 0; j < 4; ++j)
        acc[i][j] = __builtin_amdgcn_mfma_f32_16x16x32_bf16(af[i], bfr[j], acc[i][j], 0, 0, 0);
    SC0(); SB();                    // reads-done barrier (before next overwrite)
    cur ^= 1;
  }

#pragma unroll
  for (int i = 0; i < 4; ++i) {
    const int rbase = m0 + wm * 64 + i * 16 + quad * 4;
#pragma unroll
    for (int j = 0; j < 4; ++j) {
      const int c = n0 + wn * 64 + j * 16 + l15;
#pragma unroll
      for (int r = 0; r < 4; ++r)
        Cb[(size_t)b * sC + (size_t)(rbase + r) * Nn + c] = f2bf(acc[i][j][r]);
    }
  }
}

// standalone GEMM (layer-0 vT)
__global__ __launch_bounds__(256) void mfma_gemm_k(
    const unsigned short* __restrict__ A, const unsigned short* __restrict__ Bm,
    unsigned short* __restrict__ Cb,
    int K, int Nn, int lda, int ldb, long sA, long sB, long sC) {
  __shared__ __align__(16) unsigned short As[2][128 * 32];
  __shared__ __align__(16) unsigned short Bs[2][128 * 32];
  gemm_body(A, Bm, Cb, K, Nn, lda, ldb, sA, sB, sC,
            blockIdx.z, blockIdx.y * 128, blockIdx.x * 128, threadIdx.x, As, Bs);
}

// fused per-layer projections: blocks 0..511 = qk-proj, 512..767 = vT
__global__ __launch_bounds__(256) void gemm2_k(
    const unsigned short* __restrict__ A1, const unsigned short* __restrict__ B1,
    unsigned short* __restrict__ C1,
    const unsigned short* __restrict__ A2, const unsigned short* __restrict__ B2,
    unsigned short* __restrict__ C2) {
  __shared__ __align__(16) unsigned short As[2][128 * 32];
  __shared__ __align__(16) unsigned short Bs[2][128 * 32];
  const int bx = blockIdx.x;
  if (bx < 512) {
    // qk = f @ [WQ;WK]^T : M=BN, N=512, K=256
    gemm_body(A1, B1, C1, H_, 2 * H_, H_, H_, 0, 0, 0,
              0, (bx >> 2) * 128, (bx & 3) * 128, threadIdx.x, As, Bs);
  } else {
    // vT[b] = WV @ f[b]^T : M=256, N=512, K=256 per batch
    const int v = bx - 512;
    gemm_body(A2, B2, C2, H_, N_, H_, H_, 0, SF_, SVT_,
              v >> 3, ((v >> 2) & 1) * 128, (v & 3) * 128, threadIdx.x, As, Bs);
  }
}

// ========== mega_k: [QK^T+softmax | prior] + PV + LN + FFN(2 GEMMs) + LN, one layer end-to-end ==========
// 64 rows/block, 1024 threads (16 waves = 4 waves/SIMD for latency hiding). Grid (B, N/64) batch-major.
// Phase A wave grid 2x8 (acc[2][4]); PV/FFN wave grid 2x8 (acc[2][2]). Dbuf + __syncthreads per K-step.
template<int PRIOR, int LAST>
__global__ __launch_bounds__(1024) void mega_k(
    const unsigned short* __restrict__ qk, const float* __restrict__ prior,
    const float* __restrict__ masks, const float* __restrict__ guide,
    const unsigned short* __restrict__ vT, const unsigned short* __restrict__ resb,
    const unsigned short* __restrict__ w1, const float* __restrict__ b1,
    const unsigned short* __restrict__ w2, const float* __restrict__ b2,
    float* __restrict__ att, unsigned short* __restrict__ fbout,
    float* __restrict__ outx) {
  __shared__ __align__(16) unsigned short As[2][64 * 32];     // 8 KB
  __shared__ __align__(16) unsigned short Bs[2][512 * 32];    // 64 KB
  __shared__ __align__(16) unsigned short PsU[64 * 528];      // 67.5 KB: Ps(520) / {Pb,T1}(264)
  __shared__ float red[8][64][2];                             // 4 KB
  const int b = blockIdx.x;
  const int t = threadIdx.x;
  const int wave = t >> 6, lane = t & 63;                     // wave 0..15
  const int quad = lane >> 4, l15 = lane & 15;
  const int m0 = blockIdx.y * 64;
  const int srow = lane >> 2;
  const int kc = KC_STAGE(lane);
  const int pos8 = (lane & 3) * 8;
  const int soff = KC_READ(quad, l15);
  const int wm = wave >> 3, wn = wave & 7;                    // 2x8 wave grid (all phases)

  // Phase-B V staging pointer (16 waves cover all 256 V rows, 1 call each)
  const unsigned short* pv = vT + (size_t)b * SVT_ + (size_t)(wave * 16 + srow) * N_ + kc;
  const int lvo = (wave * 16 + srow) * 32 + pos8;

  if (PRIOR) {
    // early V tile-0 prefetch, hidden under the prior copy
    async16(pv, &Bs[0][lvo]);
    const f32x4* src = (const f32x4*)(prior + ((size_t)b * N_ + m0) * N_);
    f32x4*       dst = (f32x4*)(att   + ((size_t)b * N_ + m0) * N_);
#pragma unroll
    for (int s = 0; s < 8; ++s) {
      int idx4 = s * 1024 + t;
      f32x4 v = __builtin_nontemporal_load(&src[idx4]);
      __builtin_nontemporal_store(v, &dst[idx4]);
      int row = idx4 >> 7, col4 = idx4 & 127;
      ushort4 o;
      o.x = f2bf(v.x); o.y = f2bf(v.y); o.z = f2bf(v.z); o.w = f2bf(v.w);
      *(ushort4*)&PsU[row * 520 + col4 * 4] = o;
    }
    __syncthreads();   // Ps visible + V tile-0 staged
  } else {
    // ---- Phase A: QK^T (64 q-rows x 512 keys, K=256) ----
    const int ld = 2 * H_;
    const unsigned short* base = qk + (size_t)b * N_ * ld;
    const unsigned short* pa = base + (size_t)(m0 + wave * 16 + srow) * ld + kc;   // waves 0..3
    const unsigned short* pb = base + H_ + (size_t)(wave * 32 + srow) * ld + kc;   // 2 chunks of 16 rows
    const int lao = (wave * 16 + srow) * 32 + pos8;
    const int lbo = (wave * 32 + srow) * 32 + pos8;

    f32x4 acc[2][4];
#pragma unroll
    for (int i = 0; i < 2; ++i)
#pragma unroll
      for (int j = 0; j < 4; ++j) acc[i][j] = (f32x4){0.f, 0.f, 0.f, 0.f};

    if (wave < 4) async16(pa, &As[0][lao]);
#pragma unroll
    for (int c = 0; c < 2; ++c)
      async16(pb + (size_t)c * 16 * ld, &Bs[0][lbo + c * 16 * 32]);
    __syncthreads();
    int cur = 0;
#pragma unroll
    for (int tt = 0; tt < 8; ++tt) {
      if (tt < 7) {
        const int kn = (tt + 1) * 32;
        if (wave < 4) async16(pa + kn, &As[cur ^ 1][lao]);
#pragma unroll
        for (int c = 0; c < 2; ++c)
          async16(pb + (size_t)c * 16 * ld + kn, &Bs[cur ^ 1][lbo + c * 16 * 32]);
      }
      bf16x8 af[2], bfr[4];
#pragma unroll
      for (int i = 0; i < 2; ++i)
        af[i] = *(const bf16x8*)&As[cur][(wm * 32 + i * 16 + l15) * 32 + soff];
#pragma unroll
      for (int j = 0; j < 4; ++j)
        bfr[j] = *(const bf16x8*)&Bs[cur][(wn * 64 + j * 16 + l15) * 32 + soff];
#pragma unroll
      for (int i = 0; i < 2; ++i)
#pragma unroll
        for (int j = 0; j < 4; ++j)
          acc[i][j] = __builtin_amdgcn_mfma_f32_16x16x32_bf16(af[i], bfr[j], acc[i][j], 0, 0, 0);
      __syncthreads();
      cur ^= 1;
    }

    // early V tile-0 prefetch, hidden under the 3-pass softmax
    async16(pv, &Bs[0][lvo]);

    // logits + row-max
    float am[4];
#pragma unroll
    for (int j = 0; j < 4; ++j) {
      float mv = masks[(size_t)b * N_ + wn * 64 + j * 16 + l15];
      am[j] = (mv != 0.f) ? 0.f : BIGF;
    }
#pragma unroll
    for (int i = 0; i < 2; ++i) {
#pragma unroll
      for (int r = 0; r < 4; ++r) {
        const int mloc = wm * 32 + i * 16 + quad * 4 + r;
        const float* gr = guide + ((size_t)b * N_ + m0 + mloc) * N_;
        float mx = -BIGF;
#pragma unroll
        for (int j = 0; j < 4; ++j) {
          const int c = wn * 64 + j * 16 + l15;
          float g = __builtin_nontemporal_load(&gr[c]);
          float v = acc[i][j][r] * 0.0625f - am[j] - ((g != 0.f) ? 0.f : BIGF);
          acc[i][j][r] = v;
          mx = fmaxf(mx, v);
        }
#pragma unroll
        for (int off = 1; off < 16; off <<= 1) mx = fmaxf(mx, __shfl_xor(mx, off));
        if (l15 == 0) red[wn][mloc][0] = mx;
      }
    }
    __syncthreads();
    // exp + row-sum
#pragma unroll
    for (int i = 0; i < 2; ++i) {
#pragma unroll
      for (int r = 0; r < 4; ++r) {
        const int mloc = wm * 32 + i * 16 + quad * 4 + r;
        float M = red[0][mloc][0];
#pragma unroll
        for (int w = 1; w < 8; ++w) M = fmaxf(M, red[w][mloc][0]);
        float s = 0.f;
#pragma unroll
        for (int j = 0; j < 4; ++j) {
          float e = __expf(acc[i][j][r] - M);
          acc[i][j][r] = e;
          s += e;
        }
#pragma unroll
        for (int off = 1; off < 16; off <<= 1) s += __shfl_xor(s, off);
        if (l15 == 0) red[wn][mloc][1] = s;
      }
    }
    __syncthreads();
    // normalize -> att fp32 (NT) + Ps bf16
#pragma unroll
    for (int i = 0; i < 2; ++i) {
#pragma unroll
      for (int r = 0; r < 4; ++r) {
        const int mloc = wm * 32 + i * 16 + quad * 4 + r;
        float S = red[0][mloc][1];
#pragma unroll
        for (int w = 1; w < 8; ++w) S += red[w][mloc][1];
        float inv = 1.f / S;
        const size_t rowoff = ((size_t)b * N_ + m0 + mloc) * N_;
#pragma unroll
        for (int j = 0; j < 4; ++j) {
          const int c = wn * 64 + j * 16 + l15;
          float o = acc[i][j][r] * inv;
          __builtin_nontemporal_store(o, &att[rowoff + c]);
          PsU[mloc * 520 + c] = f2bf(o);
        }
      }
    }
    __syncthreads();   // Ps visible + V tile-0 staged
  }

  // ---- Phase B: post = LN(P @ vT^T + f)  (post stays in acc2 registers) ----
  f32x4 acc2[2][2];
#pragma unroll
  for (int i = 0; i < 2; ++i)
#pragma unroll
    for (int j = 0; j < 2; ++j) acc2[i][j] = (f32x4){0.f, 0.f, 0.f, 0.f};

  int cur = 0;   // V tile 0 already staged in Bs[0]
#pragma unroll
  for (int tt = 0; tt < 16; ++tt) {
    if (tt < 15) {
      async16(pv + (tt + 1) * 32, &Bs[cur ^ 1][lvo]);
    }
    bf16x8 af[2], bfr[2];
#pragma unroll
    for (int i = 0; i < 2; ++i)
      af[i] = *(const bf16x8*)&PsU[(wm * 32 + i * 16 + l15) * 520 + tt * 32 + quad * 8];
#pragma unroll
    for (int j = 0; j < 2; ++j)
      bfr[j] = *(const bf16x8*)&Bs[cur][(wn * 32 + j * 16 + l15) * 32 + soff];
#pragma unroll
    for (int i = 0; i < 2; ++i)
#pragma unroll
      for (int j = 0; j < 2; ++j)
        acc2[i][j] = __builtin_amdgcn_mfma_f32_16x16x32_bf16(af[i], bfr[j], acc2[i][j], 0, 0, 0);
    __syncthreads();
    cur ^= 1;
  }

  // FFN staging pointers; stage W1 tile 0 now (Bs[0] free: last read tt=14, barrier passed).
  const unsigned short* pw1 = w1 + (size_t)(wave * 16 + srow) * H_ + kc;
  const unsigned short* pw2 = w2 + (size_t)(wave * 16 + srow) * H_ + kc;
  async16(pw1, &Bs[0][lvo]);

  // residual + LN pass 1
#pragma unroll
  for (int i = 0; i < 2; ++i) {
#pragma unroll
    for (int r = 0; r < 4; ++r) {
      const int mloc = wm * 32 + i * 16 + quad * 4 + r;
      const long grow = (long)b * N_ + m0 + mloc;
      float s = 0.f, q = 0.f;
#pragma unroll
      for (int j = 0; j < 2; ++j) {
        const int c = wn * 32 + j * 16 + l15;
        float v = acc2[i][j][r] + bf2f(resb[grow * H_ + c]);
        acc2[i][j][r] = v;
        s += v; q += v * v;
      }
#pragma unroll
      for (int off = 1; off < 16; off <<= 1) {
        s += __shfl_xor(s, off);
        q += __shfl_xor(q, off);
      }
      if (l15 == 0) { red[wn][mloc][0] = s; red[wn][mloc][1] = q; }
    }
  }
  __syncthreads();
  // LN pass 2: normalize in regs + write bf16 A-operand copy (Pb) to LDS
  unsigned short* Pb  = PsU;              // stride 264, overlays dead Ps
  unsigned short* T1p = PsU + 64 * 264;   // stride 264
#pragma unroll
  for (int i = 0; i < 2; ++i) {
#pragma unroll
    for (int r = 0; r < 4; ++r) {
      const int mloc = wm * 32 + i * 16 + quad * 4 + r;
      float S = red[0][mloc][0], Q = red[0][mloc][1];
#pragma unroll
      for (int w = 1; w < 8; ++w) { S += red[w][mloc][0]; Q += red[w][mloc][1]; }
      float mu = S * (1.f / H_);
      float var = Q * (1.f / H_) - mu * mu;
      float inv = 1.f / sqrtf(var + EPSF);
#pragma unroll
      for (int j = 0; j < 2; ++j) {
        const int c = wn * 32 + j * 16 + l15;
        float o = (acc2[i][j][r] - mu) * inv;
        acc2[i][j][r] = o;                       // post kept in regs (FFN residual)
        Pb[mloc * 264 + c] = f2bf(o);
      }
    }
  }
  __syncthreads();   // Pb visible + W1 tile-0 staged

  // ---- FFN phase 1: t1 = relu(post @ W1^T + b1) -> T1 (LDS) ----
  {
    f32x4 acc3[2][2];
#pragma unroll
    for (int i = 0; i < 2; ++i)
#pragma unroll
      for (int j = 0; j < 2; ++j) acc3[i][j] = (f32x4){0.f, 0.f, 0.f, 0.f};
    cur = 0;
#pragma unroll
    for (int tt = 0; tt < 8; ++tt) {
      if (tt < 7) {
        async16(pw1 + (tt + 1) * 32, &Bs[cur ^ 1][lvo]);
      }
      bf16x8 af[2], bfr[2];
#pragma unroll
      for (int i = 0; i < 2; ++i)
        af[i] = *(const bf16x8*)&Pb[(wm * 32 + i * 16 + l15) * 264 + tt * 32 + quad * 8];
#pragma unroll
      for (int j = 0; j < 2; ++j)
        bfr[j] = *(const bf16x8*)&Bs[cur][(wn * 32 + j * 16 + l15) * 32 + soff];
#pragma unroll
      for (int i = 0; i < 2; ++i)
#pragma unroll
        for (int j = 0; j < 2; ++j)
          acc3[i][j] = __builtin_amdgcn_mfma_f32_16x16x32_bf16(af[i], bfr[j], acc3[i][j], 0, 0, 0);
      __syncthreads();
      cur ^= 1;
    }

    // stage W2 tile 0 into Bs[0] (last read tt=6, barrier passed); hidden under bias/relu/T1 write
    async16(pw2, &Bs[0][lvo]);

    float bv[2];
#pragma unroll
    for (int j = 0; j < 2; ++j) bv[j] = b1[wn * 32 + j * 16 + l15];
#pragma unroll
    for (int i = 0; i < 2; ++i) {
#pragma unroll
      for (int r = 0; r < 4; ++r) {
        const int mloc = wm * 32 + i * 16 + quad * 4 + r;
#pragma unroll
        for (int j = 0; j < 2; ++j) {
          const int c = wn * 32 + j * 16 + l15;
          T1p[mloc * 264 + c] = f2bf(fmaxf(acc3[i][j][r] + bv[j], 0.f));
        }
      }
    }
  }
  __syncthreads();   // T1 visible + W2 tile-0 staged

  // ---- FFN phase 2: x = LN(T1 @ W2^T + b2 + post) * mask ----
  {
    f32x4 acc4[2][2];
#pragma unroll
    for (int i = 0; i < 2; ++i)
#pragma unroll
      for (int j = 0; j < 2; ++j) acc4[i][j] = (f32x4){0.f, 0.f, 0.f, 0.f};
    cur = 0;
#pragma unroll
    for (int tt = 0; tt < 8; ++tt) {
      if (tt < 7) {
        async16(pw2 + (tt + 1) * 32, &Bs[cur ^ 1][lvo]);
      }
      bf16x8 af[2], bfr[2];
#pragma unroll
      for (int i = 0; i < 2; ++i)
        af[i] = *(const bf16x8*)&T1p[(wm * 32 + i * 16 + l15) * 264 + tt * 32 + quad * 8];
#pragma unroll
      for (int j = 0; j < 2; ++j)
        bfr[j] = *(const bf16x8*)&Bs[cur][(wn * 32 + j * 16 + l15) * 32 + soff];
#pragma unroll
      for (int i = 0; i < 2; ++i)
#pragma unroll
        for (int j = 0; j < 2; ++j)
          acc4[i][j] = __builtin_amdgcn_mfma_f32_16x16x32_bf16(af[i], bfr[j], acc4[i][j], 0, 0, 0);
      __syncthreads();
      cur ^= 1;
    }
    float bv[2];
#pragma unroll
    for (int j = 0; j < 2; ++j) bv[j] = b2[wn * 32 + j * 16 + l15];
#pragma unroll
    for (int i = 0; i < 2; ++i) {
#pragma unroll
      for (int r = 0; r < 4; ++r) {
        const int mloc = wm * 32 + i * 16 + quad * 4 + r;
        float s = 0.f, q = 0.f;
#pragma unroll
        for (int j = 0; j < 2; ++j) {
          float v = acc4[i][j][r] + bv[j] + acc2[i][j][r];   // residual from registers
          acc4[i][j][r] = v;
          s += v; q += v * v;
        }
#pragma unroll
        for (int off = 1; off < 16; off <<= 1) {
          s += __shfl_xor(s, off);
          q += __shfl_xor(q, off);
        }
        if (l15 == 0) { red[wn][mloc][0] = s; red[wn][mloc][1] = q; }
      }
    }
    __syncthreads();
#pragma unroll
    for (int i = 0; i < 2; ++i) {
#pragma unroll
      for (int r = 0; r < 4; ++r) {
        const int mloc = wm * 32 + i * 16 + quad * 4 + r;
        const long grow = (long)b * N_ + m0 + mloc;
        float S = red[0][mloc][0], Q = red[0][mloc][1];
#pragma unroll
        for (int w = 1; w < 8; ++w) { S += red[w][mloc][0]; Q += red[w][mloc][1]; }
        float mu = S * (1.f / H_);
        float var = Q * (1.f / H_) - mu * mu;
        float inv = 1.f / sqrtf(var + EPSF);
        float mval = masks[grow];
#pragma unroll
        for (int j = 0; j < 2; ++j) {
          const int c = wn * 32 + j * 16 + l15;
          float o = (acc4[i][j][r] - mu) * inv * mval;
          if (LAST) __builtin_nontemporal_store(o, &outx[grow * H_ + c]);
          else      fbout[grow * H_ + c] = f2bf(o);
        }
      }
    }
  }
}

extern "C" void kernel_launch(void* const* d_in, const int* in_sizes, int n_in,
                              void* d_out, int out_size, void* d_ws, size_t ws_size,
                              hipStream_t stream) {
  const float* features = (const float*)d_in[0];
  const float* masks    = (const float*)d_in[1];
  const float* guide    = (const float*)d_in[2];
  const float* prior    = (const float*)d_in[3];
  const float* WQ       = (const float*)d_in[4];
  const float* WK       = (const float*)d_in[5];
  const float* WV       = (const float*)d_in[6];
  const float* W1       = (const float*)d_in[7];
  const float* b1       = (const float*)d_in[8];
  const float* W2       = (const float*)d_in[9];
  const float* b2       = (const float*)d_in[10];

  float* out     = (float*)d_out;
  float* out_x   = out;
  float* out_att = out + (size_t)BN_ * H_;

  char* w = (char*)d_ws;
  unsigned short* f_bf   = (unsigned short*)w; w += (size_t)BN_ * H_ * 2;        // 8 MB
  unsigned short* qk_bf  = (unsigned short*)w; w += (size_t)BN_ * 2 * H_ * 2;    // 16 MB
  unsigned short* vT     = (unsigned short*)w; w += (size_t)BN_ * H_ * 2;        // 8 MB
  unsigned short* wqk_bf = (unsigned short*)w; w += (size_t)S_ * 2 * HH_ * 2;
  unsigned short* wv_bf  = (unsigned short*)w; w += (size_t)S_ * HH_ * 2;
  unsigned short* w1_bf  = (unsigned short*)w; w += (size_t)S_ * HH_ * 2;
  unsigned short* w2_bf  = (unsigned short*)w; w += (size_t)S_ * HH_ * 2;

  dim3 g_cvt(5 * S_ * HH_ / 1024);
  dim3 g_ew(BN_ * H_ / 1024);
  dim3 g_vt(4, 2, B_);                 // layer-0 vT
  dim3 g_g2(768);                      // fused qk-proj (512) + vT (256)
  dim3 g_mega(B_, N_ / 64);            // full layer: 256 blocks, batch-major

  cvt_all_k<<<g_cvt, 256, 0, stream>>>(WQ, WK, WV, W1, W2, wqk_bf, wv_bf, w1_bf, w2_bf);
  mask_mul_k<<<g_ew, 256, 0, stream>>>(features, masks, f_bf);

  for (int i = 0; i < S_; ++i) {
    float* att = out_att + (size_t)i * B_ * N_ * N_;
    const unsigned short* w1p = w1_bf + (size_t)i * HH_;
    const unsigned short* w2p = w2_bf + (size_t)i * HH_;
    const float* b1p = b1 + (size_t)i * H_;
    const float* b2p = b2 + (size_t)i * H_;
    if (i == 0) {
      mfma_gemm_k<<<g_vt, 256, 0, stream>>>(wv_bf, f_bf, vT, H_, N_, H_, H_, 0, SF_, SVT_);
      mega_k<1, 0><<<g_mega, 1024, 0, stream>>>(nullptr, prior, masks, nullptr,
                                                vT, f_bf, w1p, b1p, w2p, b2p,
                                                att, f_bf, nullptr);
    } else {
      gemm2_k<<<g_g2, 256, 0, stream>>>(f_bf, wqk_bf + (size_t)i * 2 * HH_, qk_bf,
                                        wv_bf + (size_t)i * HH_, f_bf, vT);
      if (i < S_ - 1) {
        mega_k<0, 0><<<g_mega, 1024, 0, stream>>>(qk_bf, nullptr, masks, guide,
                                                  vT, f_bf, w1p, b1p, w2p, b2p,
                                                  att, f_bf, nullptr);
      } else {
        mega_k<0, 1><<<g_mega, 1024, 0, stream>>>(qk_bf, nullptr, masks, guide,
                                                  vT, f_bf, w1p, b1p, w2p, b2p,
                                                  att, nullptr, out_x);
      }
    }
  }
}

// Round 9
// 337.912 us; speedup vs baseline: 1.0390x; 1.0390x over previous
//
#include <hip/hip_runtime.h>
#include <cstdint>
#include <cstddef>

#define B_ 32
#define N_ 512
#define H_ 256
#define S_ 3
#define BN_ (B_*N_)            // 16384
#define HH_ (H_*H_)            // 65536
#define BIGF 3.4028234e+38f
#define EPSF 1e-5f
#define SF_ ((long)N_ * H_)    // 131072
#define SVT_ ((long)H_ * N_)   // 131072

typedef __bf16 bf16x8 __attribute__((ext_vector_type(8)));
typedef float  f32x4  __attribute__((ext_vector_type(4)));

typedef const void __attribute__((address_space(1)))* gas_t;
typedef void __attribute__((address_space(3)))* las_t;

// async global->LDS, 16B per lane. LDS dest must be wave-uniform base + lane*16.
__device__ __forceinline__ void async16(const unsigned short* g, unsigned short* l) {
  __builtin_amdgcn_global_load_lds((gas_t)g, (las_t)l, 16, 0, 0);
}

__device__ __forceinline__ unsigned short f2bf(float f) {
  __bf16 h = (__bf16)f;
  unsigned short s;
  __builtin_memcpy(&s, &h, 2);
  return s;
}
__device__ __forceinline__ float bf2f(unsigned short u) {
  unsigned int v = ((unsigned int)u) << 16;
  float f;
  __builtin_memcpy(&f, &v, 4);
  return f;
}

// XOR-swizzle for 32-short (64B) LDS rows, 4 chunks of 8 shorts.
#define KC_STAGE(lane) ((((lane) & 3) ^ (((lane) >> 3) & 3)) * 8)
#define KC_READ(quad, l15) ((((quad) ^ (((l15) >> 1) & 3))) * 8)

// ------------- merged init: 5 weight tensors -> bf16  AND  f_bf = bf16(x*mask) -------------
// blocks 0..959: weight convert (exact boundary: 245760/256=960); blocks 960..5055: mask-mul.
__global__ __launch_bounds__(256) void init_k(
    const float* __restrict__ WQ, const float* __restrict__ WK,
    const float* __restrict__ WV, const float* __restrict__ W1,
    const float* __restrict__ W2,
    unsigned short* __restrict__ wqk, unsigned short* __restrict__ wv,
    unsigned short* __restrict__ w1, unsigned short* __restrict__ w2,
    const float* __restrict__ x, const float* __restrict__ masks,
    unsigned short* __restrict__ fb) {
  const int per = S_ * HH_ / 4;        // 49152 float4 per weight tensor
  const int wtot = 5 * per;            // 245760
  int gi = blockIdx.x * 256 + threadIdx.x;
  if (gi < wtot) {
    int which = gi / per;
    int e4 = gi - which * per;
    float4 v;
    if      (which == 0) v = ((const float4*)WQ)[e4];
    else if (which == 1) v = ((const float4*)WK)[e4];
    else if (which == 2) v = ((const float4*)WV)[e4];
    else if (which == 3) v = ((const float4*)W1)[e4];
    else                 v = ((const float4*)W2)[e4];
    ushort4 o;
    o.x = f2bf(v.x); o.y = f2bf(v.y); o.z = f2bf(v.z); o.w = f2bf(v.w);
    int e = e4 * 4;
    if (which <= 1) {
      int L = e / HH_, off = e - L * HH_;
      *(ushort4*)&wqk[(size_t)L * 2 * HH_ + (which == 1 ? HH_ : 0) + off] = o;
    } else if (which == 2) ((ushort4*)wv)[e4] = o;
    else if   (which == 3) ((ushort4*)w1)[e4] = o;
    else                   ((ushort4*)w2)[e4] = o;
  } else {
    int i = gi - wtot;                 // float4 index into features
    int row = i >> 6;
    float m = masks[row];
    float4 v = ((const float4*)x)[i];
    ushort4 o;
    o.x = f2bf(v.x * m); o.y = f2bf(v.y * m); o.z = f2bf(v.z * m); o.w = f2bf(v.w * m);
    ((ushort4*)fb)[i] = o;
  }
}

// ================= MFMA GEMM body (128x128, BK=32, dbuf prefetch, 1 barrier/step) =================
// C = A(bf16,[m][k],lda) @ B(bf16,[n][k],ldb)^T   (bf16 out)
__device__ __forceinline__ void gemm_body(
    const unsigned short* __restrict__ A, const unsigned short* __restrict__ Bm,
    unsigned short* __restrict__ Cb,
    int K, int Nn, int lda, int ldb, long sA, long sB, long sC,
    int b, int m0, int n0, int t,
    unsigned short (&As)[2][128 * 32], unsigned short (&Bs)[2][128 * 32]) {
  const int wave = t >> 6, lane = t & 63;
  const int wm = wave >> 1, wn = wave & 1;
  const int quad = lane >> 4, l15 = lane & 15;
  const int srow = lane >> 2;
  const int kc = KC_STAGE(lane);
  const int pos8 = (lane & 3) * 8;

  const unsigned short* pa0 = A + (size_t)b * sA + (size_t)(m0 + wave * 32 + srow) * lda + kc;
  const unsigned short* pa1 = pa0 + 16 * (size_t)lda;
  const unsigned short* pb0 = Bm + (size_t)b * sB + (size_t)(n0 + wave * 32 + srow) * ldb + kc;
  const unsigned short* pb1 = pb0 + 16 * (size_t)ldb;
  const int lo = (wave * 32 + srow) * 32 + pos8;

  f32x4 acc[4][4];
#pragma unroll
  for (int i = 0; i < 4; ++i)
#pragma unroll
    for (int j = 0; j < 4; ++j) acc[i][j] = (f32x4){0.f, 0.f, 0.f, 0.f};

  const int soff = KC_READ(quad, l15);
  const int NT = K >> 5;
  async16(pa0, &As[0][lo]); async16(pa1, &As[0][lo + 16 * 32]);
  async16(pb0, &Bs[0][lo]); async16(pb1, &Bs[0][lo + 16 * 32]);
  __syncthreads();
  int cur = 0;
  for (int tt = 0; tt < NT; ++tt) {
    if (tt + 1 < NT) {
      const int kn = (tt + 1) << 5;
      async16(pa0 + kn, &As[cur ^ 1][lo]); async16(pa1 + kn, &As[cur ^ 1][lo + 16 * 32]);
      async16(pb0 + kn, &Bs[cur ^ 1][lo]); async16(pb1 + kn, &Bs[cur ^ 1][lo + 16 * 32]);
    }
    bf16x8 af[4], bfr[4];
#pragma unroll
    for (int i = 0; i < 4; ++i)
      af[i] = *(const bf16x8*)&As[cur][(wm * 64 + i * 16 + l15) * 32 + soff];
#pragma unroll
    for (int j = 0; j < 4; ++j)
      bfr[j] = *(const bf16x8*)&Bs[cur][(wn * 64 + j * 16 + l15) * 32 + soff];
#pragma unroll
    for (int i = 0; i < 4; ++i)
#pragma unroll
      for (int j = 0; j < 4; ++j)
        acc[i][j] = __builtin_amdgcn_mfma_f32_16x16x32_bf16(af[i], bfr[j], acc[i][j], 0, 0, 0);
    __syncthreads();
    cur ^= 1;
  }

#pragma unroll
  for (int i = 0; i < 4; ++i) {
    const int rbase = m0 + wm * 64 + i * 16 + quad * 4;
#pragma unroll
    for (int j = 0; j < 4; ++j) {
      const int c = n0 + wn * 64 + j * 16 + l15;
#pragma unroll
      for (int r = 0; r < 4; ++r)
        Cb[(size_t)b * sC + (size_t)(rbase + r) * Nn + c] = f2bf(acc[i][j][r]);
    }
  }
}

// standalone GEMM (layer-0 vT)
__global__ __launch_bounds__(256) void mfma_gemm_k(
    const unsigned short* __restrict__ A, const unsigned short* __restrict__ Bm,
    unsigned short* __restrict__ Cb,
    int K, int Nn, int lda, int ldb, long sA, long sB, long sC) {
  __shared__ __align__(16) unsigned short As[2][128 * 32];
  __shared__ __align__(16) unsigned short Bs[2][128 * 32];
  gemm_body(A, Bm, Cb, K, Nn, lda, ldb, sA, sB, sC,
            blockIdx.z, blockIdx.y * 128, blockIdx.x * 128, threadIdx.x, As, Bs);
}

// fused per-layer projections: blocks 0..511 = qk-proj, 512..767 = vT
__global__ __launch_bounds__(256) void gemm2_k(
    const unsigned short* __restrict__ A1, const unsigned short* __restrict__ B1,
    unsigned short* __restrict__ C1,
    const unsigned short* __restrict__ A2, const unsigned short* __restrict__ B2,
    unsigned short* __restrict__ C2) {
  __shared__ __align__(16) unsigned short As[2][128 * 32];
  __shared__ __align__(16) unsigned short Bs[2][128 * 32];
  const int bx = blockIdx.x;
  if (bx < 512) {
    // qk = f @ [WQ;WK]^T : M=BN, N=512, K=256
    gemm_body(A1, B1, C1, H_, 2 * H_, H_, H_, 0, 0, 0,
              0, (bx >> 2) * 128, (bx & 3) * 128, threadIdx.x, As, Bs);
  } else {
    // vT[b] = WV @ f[b]^T : M=256, N=512, K=256 per batch
    const int v = bx - 512;
    gemm_body(A2, B2, C2, H_, N_, H_, H_, 0, SF_, SVT_,
              v >> 3, ((v >> 2) & 1) * 128, (v & 3) * 128, threadIdx.x, As, Bs);
  }
}

// ========== mega_k: [QK^T+softmax | prior] + PV + LN + FFN(2 GEMMs) + LN, one layer end-to-end ==========
// 64 rows/block, 512 threads (8 waves). Grid (B, N/64) batch-major for XCD/L2 locality.
// post stays in registers between PV-LN and FFN (identical 2x4 wave mapping); its bf16 A-operand copy
// and T1 overlay the then-dead Ps buffer. LDS total 141.5 KB -> 1 block/CU, everything block-local.
template<int PRIOR, int LAST>
__global__ __launch_bounds__(512) void mega_k(
    const unsigned short* __restrict__ qk, const float* __restrict__ prior,
    const float* __restrict__ masks, const float* __restrict__ guide,
    const unsigned short* __restrict__ vT, const unsigned short* __restrict__ resb,
    const unsigned short* __restrict__ w1, const float* __restrict__ b1,
    const unsigned short* __restrict__ w2, const float* __restrict__ b2,
    float* __restrict__ att, unsigned short* __restrict__ fbout,
    float* __restrict__ outx) {
  __shared__ __align__(16) unsigned short As[2][64 * 32];     // 8 KB
  __shared__ __align__(16) unsigned short Bs[2][512 * 32];    // 64 KB
  __shared__ __align__(16) unsigned short PsU[64 * 528];      // 67.5 KB: Ps(520) / {Pb,T1}(264)
  __shared__ float red[4][64][2];                             // 2 KB
  const int b = blockIdx.x;
  const int t = threadIdx.x;
  const int wave = t >> 6, lane = t & 63;
  const int quad = lane >> 4, l15 = lane & 15;
  const int m0 = blockIdx.y * 64;
  const int srow = lane >> 2;
  const int kc = KC_STAGE(lane);
  const int pos8 = (lane & 3) * 8;
  const int soff = KC_READ(quad, l15);

  // Phase-B V staging pointers (declared early for cross-phase prefetch)
  const unsigned short* vb = vT + (size_t)b * SVT_;
  const unsigned short* pv0 = vb + (size_t)(wave * 16 + srow) * N_ + kc;  // rows 0..127
  const unsigned short* pv1 = pv0 + (size_t)128 * N_;                     // rows 128..255
  const int lvo = (wave * 16 + srow) * 32 + pos8;

  if (PRIOR) {
    // early V tile-0 prefetch, hidden under the prior copy
    async16(pv0, &Bs[0][lvo]);
    async16(pv1, &Bs[0][lvo + 128 * 32]);
    const float* src = prior + ((size_t)b * N_ + m0) * N_;
    float*       dst = att   + ((size_t)b * N_ + m0) * N_;
#pragma unroll
    for (int s = 0; s < 16; ++s) {
      int idx4 = s * 512 + t;
      float4 v = ((const float4*)src)[idx4];
      ((float4*)dst)[idx4] = v;
      int row = idx4 >> 7, col4 = idx4 & 127;
      ushort4 o;
      o.x = f2bf(v.x); o.y = f2bf(v.y); o.z = f2bf(v.z); o.w = f2bf(v.w);
      *(ushort4*)&PsU[row * 520 + col4 * 4] = o;
    }
    __syncthreads();   // Ps visible + V tile-0 staged
  } else {
    // ---- Phase A: QK^T ----
    const int wm = wave >> 2, wn = wave & 3;
    const int ld = 2 * H_;
    const unsigned short* base = qk + (size_t)b * N_ * ld;
    const unsigned short* pa = base + (size_t)(m0 + wave * 16 + srow) * ld + kc;   // waves 0..3
    const unsigned short* pb = base + H_ + (size_t)(wave * 64 + srow) * ld + kc;
    const int lao = (wave * 16 + srow) * 32 + pos8;
    const int lbo = (wave * 64 + srow) * 32 + pos8;

    f32x4 acc[2][8];
#pragma unroll
    for (int i = 0; i < 2; ++i)
#pragma unroll
      for (int j = 0; j < 8; ++j) acc[i][j] = (f32x4){0.f, 0.f, 0.f, 0.f};

    if (wave < 4) async16(pa, &As[0][lao]);
#pragma unroll
    for (int c = 0; c < 4; ++c)
      async16(pb + (size_t)c * 16 * ld, &Bs[0][lbo + c * 16 * 32]);
    __syncthreads();
    int cur = 0;
#pragma unroll
    for (int tt = 0; tt < 8; ++tt) {
      if (tt < 7) {
        const int kn = (tt + 1) * 32;
        if (wave < 4) async16(pa + kn, &As[cur ^ 1][lao]);
#pragma unroll
        for (int c = 0; c < 4; ++c)
          async16(pb + (size_t)c * 16 * ld + kn, &Bs[cur ^ 1][lbo + c * 16 * 32]);
      }
      bf16x8 af[2], bfr[8];
#pragma unroll
      for (int i = 0; i < 2; ++i)
        af[i] = *(const bf16x8*)&As[cur][(wm * 32 + i * 16 + l15) * 32 + soff];
#pragma unroll
      for (int j = 0; j < 8; ++j)
        bfr[j] = *(const bf16x8*)&Bs[cur][(wn * 128 + j * 16 + l15) * 32 + soff];
#pragma unroll
      for (int i = 0; i < 2; ++i)
#pragma unroll
        for (int j = 0; j < 8; ++j)
          acc[i][j] = __builtin_amdgcn_mfma_f32_16x16x32_bf16(af[i], bfr[j], acc[i][j], 0, 0, 0);
      __syncthreads();
      cur ^= 1;
    }

    // early V tile-0 prefetch, hidden under the 3-pass softmax
    async16(pv0, &Bs[0][lvo]);
    async16(pv1, &Bs[0][lvo + 128 * 32]);

    // logits + row-max
    float am[8];
#pragma unroll
    for (int j = 0; j < 8; ++j) {
      float mv = masks[(size_t)b * N_ + wn * 128 + j * 16 + l15];
      am[j] = (mv != 0.f) ? 0.f : BIGF;
    }
#pragma unroll
    for (int i = 0; i < 2; ++i) {
#pragma unroll
      for (int r = 0; r < 4; ++r) {
        const int mloc = wm * 32 + i * 16 + quad * 4 + r;
        const float* gr = guide + ((size_t)b * N_ + m0 + mloc) * N_;
        float mx = -BIGF;
#pragma unroll
        for (int j = 0; j < 8; ++j) {
          const int c = wn * 128 + j * 16 + l15;
          float g = gr[c];
          float v = acc[i][j][r] * 0.0625f - am[j] - ((g != 0.f) ? 0.f : BIGF);
          acc[i][j][r] = v;
          mx = fmaxf(mx, v);
        }
#pragma unroll
        for (int off = 1; off < 16; off <<= 1) mx = fmaxf(mx, __shfl_xor(mx, off));
        if (l15 == 0) red[wn][mloc][0] = mx;
      }
    }
    __syncthreads();
    // exp + row-sum
#pragma unroll
    for (int i = 0; i < 2; ++i) {
#pragma unroll
      for (int r = 0; r < 4; ++r) {
        const int mloc = wm * 32 + i * 16 + quad * 4 + r;
        float M = fmaxf(fmaxf(red[0][mloc][0], red[1][mloc][0]),
                        fmaxf(red[2][mloc][0], red[3][mloc][0]));
        float s = 0.f;
#pragma unroll
        for (int j = 0; j < 8; ++j) {
          float e = __expf(acc[i][j][r] - M);
          acc[i][j][r] = e;
          s += e;
        }
#pragma unroll
        for (int off = 1; off < 16; off <<= 1) s += __shfl_xor(s, off);
        if (l15 == 0) red[wn][mloc][1] = s;
      }
    }
    __syncthreads();
    // normalize -> att fp32 + Ps bf16
#pragma unroll
    for (int i = 0; i < 2; ++i) {
#pragma unroll
      for (int r = 0; r < 4; ++r) {
        const int mloc = wm * 32 + i * 16 + quad * 4 + r;
        float S = red[0][mloc][1] + red[1][mloc][1] + red[2][mloc][1] + red[3][mloc][1];
        float inv = 1.f / S;
        const size_t rowoff = ((size_t)b * N_ + m0 + mloc) * N_;
#pragma unroll
        for (int j = 0; j < 8; ++j) {
          const int c = wn * 128 + j * 16 + l15;
          float o = acc[i][j][r] * inv;
          att[rowoff + c] = o;
          PsU[mloc * 520 + c] = f2bf(o);
        }
      }
    }
    __syncthreads();   // Ps visible + V tile-0 staged
  }

  // ---- Phase B: post = LN(P @ vT^T + f)  (post stays in acc2 registers) ----
  const int wm2 = wave >> 2, wn2 = wave & 3;

  f32x4 acc2[2][4];
#pragma unroll
  for (int i = 0; i < 2; ++i)
#pragma unroll
    for (int j = 0; j < 4; ++j) acc2[i][j] = (f32x4){0.f, 0.f, 0.f, 0.f};

  int cur = 0;   // V tile 0 already staged in Bs[0]
#pragma unroll
  for (int tt = 0; tt < 16; ++tt) {
    if (tt < 15) {
      const int kn = (tt + 1) * 32;
      async16(pv0 + kn, &Bs[cur ^ 1][lvo]);
      async16(pv1 + kn, &Bs[cur ^ 1][lvo + 128 * 32]);
    }
    bf16x8 af[2], bfr[4];
#pragma unroll
    for (int i = 0; i < 2; ++i)
      af[i] = *(const bf16x8*)&PsU[(wm2 * 32 + i * 16 + l15) * 520 + tt * 32 + quad * 8];
#pragma unroll
    for (int j = 0; j < 4; ++j)
      bfr[j] = *(const bf16x8*)&Bs[cur][(wn2 * 64 + j * 16 + l15) * 32 + soff];
#pragma unroll
    for (int i = 0; i < 2; ++i)
#pragma unroll
      for (int j = 0; j < 4; ++j)
        acc2[i][j] = __builtin_amdgcn_mfma_f32_16x16x32_bf16(af[i], bfr[j], acc2[i][j], 0, 0, 0);
    __syncthreads();
    cur ^= 1;
  }

  // FFN staging pointers; stage W1 tile 0 now (Bs free after final PV barrier),
  // hidden under the residual+LN epilogue.
  const unsigned short* pw1  = w1 + (size_t)(wave * 16 + srow) * H_ + kc;
  const unsigned short* pw1b = pw1 + (size_t)128 * H_;
  const unsigned short* pw2  = w2 + (size_t)(wave * 16 + srow) * H_ + kc;
  const unsigned short* pw2b = pw2 + (size_t)128 * H_;
  async16(pw1,  &Bs[0][lvo]);
  async16(pw1b, &Bs[0][lvo + 128 * 32]);

  // residual + LN pass 1
#pragma unroll
  for (int i = 0; i < 2; ++i) {
#pragma unroll
    for (int r = 0; r < 4; ++r) {
      const int mloc = wm2 * 32 + i * 16 + quad * 4 + r;
      const long grow = (long)b * N_ + m0 + mloc;
      float s = 0.f, q = 0.f;
#pragma unroll
      for (int j = 0; j < 4; ++j) {
        const int c = wn2 * 64 + j * 16 + l15;
        float v = acc2[i][j][r] + bf2f(resb[grow * H_ + c]);
        acc2[i][j][r] = v;
        s += v; q += v * v;
      }
#pragma unroll
      for (int off = 1; off < 16; off <<= 1) {
        s += __shfl_xor(s, off);
        q += __shfl_xor(q, off);
      }
      if (l15 == 0) { red[wn2][mloc][0] = s; red[wn2][mloc][1] = q; }
    }
  }
  __syncthreads();
  // LN pass 2: normalize in regs + write bf16 A-operand copy (Pb) to LDS
  unsigned short* Pb  = PsU;              // stride 264, overlays dead Ps
  unsigned short* T1p = PsU + 64 * 264;   // stride 264
#pragma unroll
  for (int i = 0; i < 2; ++i) {
#pragma unroll
    for (int r = 0; r < 4; ++r) {
      const int mloc = wm2 * 32 + i * 16 + quad * 4 + r;
      float S = red[0][mloc][0] + red[1][mloc][0] + red[2][mloc][0] + red[3][mloc][0];
      float Q = red[0][mloc][1] + red[1][mloc][1] + red[2][mloc][1] + red[3][mloc][1];
      float mu = S * (1.f / H_);
      float var = Q * (1.f / H_) - mu * mu;
      float inv = 1.f / sqrtf(var + EPSF);
#pragma unroll
      for (int j = 0; j < 4; ++j) {
        const int c = wn2 * 64 + j * 16 + l15;
        float o = (acc2[i][j][r] - mu) * inv;
        acc2[i][j][r] = o;                       // post kept in regs (FFN residual)
        Pb[mloc * 264 + c] = f2bf(o);
      }
    }
  }
  __syncthreads();   // Pb visible + W1 tile-0 staged

  // ---- FFN phase 1: t1 = relu(post @ W1^T + b1) -> T1 (LDS) ----
  {
    f32x4 acc3[2][4];
#pragma unroll
    for (int i = 0; i < 2; ++i)
#pragma unroll
      for (int j = 0; j < 4; ++j) acc3[i][j] = (f32x4){0.f, 0.f, 0.f, 0.f};
    cur = 0;
#pragma unroll
    for (int tt = 0; tt < 8; ++tt) {
      if (tt < 7) {
        const int kn = (tt + 1) * 32;
        async16(pw1  + kn, &Bs[cur ^ 1][lvo]);
        async16(pw1b + kn, &Bs[cur ^ 1][lvo + 128 * 32]);
      }
      bf16x8 af[2], bfr[4];
#pragma unroll
      for (int i = 0; i < 2; ++i)
        af[i] = *(const bf16x8*)&Pb[(wm2 * 32 + i * 16 + l15) * 264 + tt * 32 + quad * 8];
#pragma unroll
      for (int j = 0; j < 4; ++j)
        bfr[j] = *(const bf16x8*)&Bs[cur][(wn2 * 64 + j * 16 + l15) * 32 + soff];
#pragma unroll
      for (int i = 0; i < 2; ++i)
#pragma unroll
        for (int j = 0; j < 4; ++j)
          acc3[i][j] = __builtin_amdgcn_mfma_f32_16x16x32_bf16(af[i], bfr[j], acc3[i][j], 0, 0, 0);
      __syncthreads();
      cur ^= 1;
    }

    // stage W2 tile 0 into Bs[0] (last read at tt=6); hidden under bias/relu/T1 write
    async16(pw2,  &Bs[0][lvo]);
    async16(pw2b, &Bs[0][lvo + 128 * 32]);

    float bv[4];
#pragma unroll
    for (int j = 0; j < 4; ++j) bv[j] = b1[wn2 * 64 + j * 16 + l15];
#pragma unroll
    for (int i = 0; i < 2; ++i) {
#pragma unroll
      for (int r = 0; r < 4; ++r) {
        const int mloc = wm2 * 32 + i * 16 + quad * 4 + r;
#pragma unroll
        for (int j = 0; j < 4; ++j) {
          const int c = wn2 * 64 + j * 16 + l15;
          T1p[mloc * 264 + c] = f2bf(fmaxf(acc3[i][j][r] + bv[j], 0.f));
        }
      }
    }
  }
  __syncthreads();   // T1 visible + W2 tile-0 staged

  // ---- FFN phase 2: x = LN(T1 @ W2^T + b2 + post) * mask ----
  {
    f32x4 acc4[2][4];
#pragma unroll
    for (int i = 0; i < 2; ++i)
#pragma unroll
      for (int j = 0; j < 4; ++j) acc4[i][j] = (f32x4){0.f, 0.f, 0.f, 0.f};
    cur = 0;
#pragma unroll
    for (int tt = 0; tt < 8; ++tt) {
      if (tt < 7) {
        const int kn = (tt + 1) * 32;
        async16(pw2  + kn, &Bs[cur ^ 1][lvo]);
        async16(pw2b + kn, &Bs[cur ^ 1][lvo + 128 * 32]);
      }
      bf16x8 af[2], bfr[4];
#pragma unroll
      for (int i = 0; i < 2; ++i)
        af[i] = *(const bf16x8*)&T1p[(wm2 * 32 + i * 16 + l15) * 264 + tt * 32 + quad * 8];
#pragma unroll
      for (int j = 0; j < 4; ++j)
        bfr[j] = *(const bf16x8*)&Bs[cur][(wn2 * 64 + j * 16 + l15) * 32 + soff];
#pragma unroll
      for (int i = 0; i < 2; ++i)
#pragma unroll
        for (int j = 0; j < 4; ++j)
          acc4[i][j] = __builtin_amdgcn_mfma_f32_16x16x32_bf16(af[i], bfr[j], acc4[i][j], 0, 0, 0);
      __syncthreads();
      cur ^= 1;
    }
    float bv[4];
#pragma unroll
    for (int j = 0; j < 4; ++j) bv[j] = b2[wn2 * 64 + j * 16 + l15];
#pragma unroll
    for (int i = 0; i < 2; ++i) {
#pragma unroll
      for (int r = 0; r < 4; ++r) {
        const int mloc = wm2 * 32 + i * 16 + quad * 4 + r;
        float s = 0.f, q = 0.f;
#pragma unroll
        for (int j = 0; j < 4; ++j) {
          float v = acc4[i][j][r] + bv[j] + acc2[i][j][r];   // residual from registers
          acc4[i][j][r] = v;
          s += v; q += v * v;
        }
#pragma unroll
        for (int off = 1; off < 16; off <<= 1) {
          s += __shfl_xor(s, off);
          q += __shfl_xor(q, off);
        }
        if (l15 == 0) { red[wn2][mloc][0] = s; red[wn2][mloc][1] = q; }
      }
    }
    __syncthreads();
#pragma unroll
    for (int i = 0; i < 2; ++i) {
#pragma unroll
      for (int r = 0; r < 4; ++r) {
        const int mloc = wm2 * 32 + i * 16 + quad * 4 + r;
        const long grow = (long)b * N_ + m0 + mloc;
        float S = red[0][mloc][0] + red[1][mloc][0] + red[2][mloc][0] + red[3][mloc][0];
        float Q = red[0][mloc][1] + red[1][mloc][1] + red[2][mloc][1] + red[3][mloc][1];
        float mu = S * (1.f / H_);
        float var = Q * (1.f / H_) - mu * mu;
        float inv = 1.f / sqrtf(var + EPSF);
        float mval = masks[grow];
#pragma unroll
        for (int j = 0; j < 4; ++j) {
          const int c = wn2 * 64 + j * 16 + l15;
          float o = (acc4[i][j][r] - mu) * inv * mval;
          if (LAST) outx[grow * H_ + c] = o;
          else      fbout[grow * H_ + c] = f2bf(o);
        }
      }
    }
  }
}

extern "C" void kernel_launch(void* const* d_in, const int* in_sizes, int n_in,
                              void* d_out, int out_size, void* d_ws, size_t ws_size,
                              hipStream_t stream) {
  const float* features = (const float*)d_in[0];
  const float* masks    = (const float*)d_in[1];
  const float* guide    = (const float*)d_in[2];
  const float* prior    = (const float*)d_in[3];
  const float* WQ       = (const float*)d_in[4];
  const float* WK       = (const float*)d_in[5];
  const float* WV       = (const float*)d_in[6];
  const float* W1       = (const float*)d_in[7];
  const float* b1       = (const float*)d_in[8];
  const float* W2       = (const float*)d_in[9];
  const float* b2       = (const float*)d_in[10];

  float* out     = (float*)d_out;
  float* out_x   = out;
  float* out_att = out + (size_t)BN_ * H_;

  char* w = (char*)d_ws;
  unsigned short* f_bf   = (unsigned short*)w; w += (size_t)BN_ * H_ * 2;        // 8 MB
  unsigned short* qk_bf  = (unsigned short*)w; w += (size_t)BN_ * 2 * H_ * 2;    // 16 MB
  unsigned short* vT     = (unsigned short*)w; w += (size_t)BN_ * H_ * 2;        // 8 MB
  unsigned short* wqk_bf = (unsigned short*)w; w += (size_t)S_ * 2 * HH_ * 2;
  unsigned short* wv_bf  = (unsigned short*)w; w += (size_t)S_ * HH_ * 2;
  unsigned short* w1_bf  = (unsigned short*)w; w += (size_t)S_ * HH_ * 2;
  unsigned short* w2_bf  = (unsigned short*)w; w += (size_t)S_ * HH_ * 2;

  dim3 g_init((5 * S_ * HH_ / 4 + BN_ * H_ / 4) / 256);  // 5056 blocks: weights + mask-mul merged
  dim3 g_vt(4, 2, B_);                 // layer-0 vT
  dim3 g_g2(768);                      // fused qk-proj (512) + vT (256)
  dim3 g_mega(B_, N_ / 64);            // full layer: 256 blocks, batch-major

  init_k<<<g_init, 256, 0, stream>>>(WQ, WK, WV, W1, W2, wqk_bf, wv_bf, w1_bf, w2_bf,
                                     features, masks, f_bf);

  for (int i = 0; i < S_; ++i) {
    float* att = out_att + (size_t)i * B_ * N_ * N_;
    const unsigned short* w1p = w1_bf + (size_t)i * HH_;
    const unsigned short* w2p = w2_bf + (size_t)i * HH_;
    const float* b1p = b1 + (size_t)i * H_;
    const float* b2p = b2 + (size_t)i * H_;
    if (i == 0) {
      mfma_gemm_k<<<g_vt, 256, 0, stream>>>(wv_bf, f_bf, vT, H_, N_, H_, H_, 0, SF_, SVT_);
      mega_k<1, 0><<<g_mega, 512, 0, stream>>>(nullptr, prior, masks, nullptr,
                                               vT, f_bf, w1p, b1p, w2p, b2p,
                                               att, f_bf, nullptr);
    } else {
      gemm2_k<<<g_g2, 256, 0, stream>>>(f_bf, wqk_bf + (size_t)i * 2 * HH_, qk_bf,
                                        wv_bf + (size_t)i * HH_, f_bf, vT);
      if (i < S_ - 1) {
        mega_k<0, 0><<<g_mega, 512, 0, stream>>>(qk_bf, nullptr, masks, guide,
                                                 vT, f_bf, w1p, b1p, w2p, b2p,
                                                 att, f_bf, nullptr);
      } else {
        mega_k<0, 1><<<g_mega, 512, 0, stream>>>(qk_bf, nullptr, masks, guide,
                                                 vT, f_bf, w1p, b1p, w2p, b2p,
                                                 att, nullptr, out_x);
      }
    }
  }
}